// Round 1
// baseline (98.286 us; speedup 1.0000x reference)
//
#include <hip/hip_runtime.h>
#include <hip/hip_bf16.h>

typedef __bf16 bf16x8 __attribute__((ext_vector_type(8)));
typedef float  f32x4  __attribute__((ext_vector_type(4)));

#define BN_EPS 1e-5f
#define NROWS 131072
#define MTILE 64              // rows per block (4 waves x 16 rows)
#define NBLOCKS (NROWS / MTILE)

// ws layout (bytes):
//   [0, 262144)        W0 packed bf16, fragment order [s][t][lane][8]
//   [262144, 264192)   a_fused f32[512]  (frame BN scale | imu BN scale)
//   [264192, 266240)   c_fused f32[512]  (frame BN shift | imu BN shift)
//   [266240, 267264)   A_fc f32[256]     (fc BN scale)
//   [267264, 268288)   C_fc f32[256]     (fc BN shift, b0 folded in)

__global__ __launch_bounds__(256) void setup_kernel(
    const float* __restrict__ W0,
    const float* __restrict__ imu_gamma, const float* __restrict__ imu_beta,
    const float* __restrict__ imu_mean,  const float* __restrict__ imu_var,
    const float* __restrict__ frame_gamma, const float* __restrict__ frame_beta,
    const float* __restrict__ frame_mean,  const float* __restrict__ frame_var,
    const float* __restrict__ b0,
    const float* __restrict__ fc_gamma, const float* __restrict__ fc_beta,
    const float* __restrict__ fc_mean,  const float* __restrict__ fc_var,
    void* __restrict__ ws)
{
    __bf16* w0p    = (__bf16*)ws;
    float* a_fused = (float*)((char*)ws + 262144);
    float* c_fused = a_fused + 512;
    float* A_fc    = c_fused + 512;
    float* C_fc    = A_fc + 256;

    const int b = blockIdx.x;
    if (b < 512) {
        // pack W0[n][k] (row-major [256,512]) into B-fragment order:
        // flat = ((s*16 + t)*64 + lane)*8 + j ; n = t*16+(lane&15); k = s*32+(lane>>4)*8+j
        const int flat = b * 256 + threadIdx.x;
        const int j    = flat & 7;
        const int lane = (flat >> 3) & 63;
        const int t    = (flat >> 9) & 15;
        const int s    = flat >> 13;
        const int n    = t * 16 + (lane & 15);
        const int k    = s * 32 + ((lane >> 4) << 3) + j;
        w0p[flat] = (__bf16)W0[n * 512 + k];
    } else {
        const int t = threadIdx.x;  // 0..255
        const float af = frame_gamma[t] / sqrtf(frame_var[t] + BN_EPS);
        a_fused[t]       = af;
        c_fused[t]       = frame_beta[t] - frame_mean[t] * af;
        const float ai = imu_gamma[t] / sqrtf(imu_var[t] + BN_EPS);
        a_fused[256 + t] = ai;
        c_fused[256 + t] = imu_beta[t] - imu_mean[t] * ai;
        const float A = fc_gamma[t] / sqrtf(fc_var[t] + BN_EPS);
        A_fc[t] = A;
        C_fc[t] = fc_beta[t] - fc_mean[t] * A + A * b0[t];  // b0 folded in
    }
}

__global__ __launch_bounds__(256, 2) void fusion_main(
    const float* __restrict__ frame, const float* __restrict__ imu,
    const float* __restrict__ W1,    const float* __restrict__ b1,
    const void* __restrict__ ws_c,   float* __restrict__ out)
{
    const __bf16* w0p      = (const __bf16*)ws_c;
    const float*  a_fused  = (const float*)((const char*)ws_c + 262144);
    const float*  c_fused  = a_fused + 512;
    const float*  A_fc     = c_fused + 512;
    const float*  C_fc     = A_fc + 256;

    __shared__ __bf16 lds[2][8192];  // double-buffered 16 KB W0 k-slice

    const int tid  = threadIdx.x;
    const int wave = tid >> 6;
    const int lane = tid & 63;
    const int r    = lane & 15;   // A-fragment row within wave tile
    const int kg   = lane >> 4;   // k-group (8 contiguous k per group)
    const size_t rowA = (size_t)blockIdx.x * MTILE + wave * 16 + r;

    // ---------- phase 1: BN+ReLU activations straight into A fragments ----------
    bf16x8 afrag[16];
    #pragma unroll
    for (int s = 0; s < 16; ++s) {
        const float* src = (s < 8) ? frame : imu;     // fused = [frame | imu]
        const int koff = (s & 7) * 32 + kg * 8;       // within-modality k
        const int kf   = s * 32 + kg * 8;             // fused k (param index)
        const float4 x0 = *(const float4*)(src + rowA * 256 + koff);
        const float4 x1 = *(const float4*)(src + rowA * 256 + koff + 4);
        const float4 a0 = *(const float4*)(a_fused + kf);
        const float4 a1 = *(const float4*)(a_fused + kf + 4);
        const float4 c0 = *(const float4*)(c_fused + kf);
        const float4 c1 = *(const float4*)(c_fused + kf + 4);
        bf16x8 v;
        v[0] = (__bf16)fmaxf(fmaf(a0.x, x0.x, c0.x), 0.f);
        v[1] = (__bf16)fmaxf(fmaf(a0.y, x0.y, c0.y), 0.f);
        v[2] = (__bf16)fmaxf(fmaf(a0.z, x0.z, c0.z), 0.f);
        v[3] = (__bf16)fmaxf(fmaf(a0.w, x0.w, c0.w), 0.f);
        v[4] = (__bf16)fmaxf(fmaf(a1.x, x1.x, c1.x), 0.f);
        v[5] = (__bf16)fmaxf(fmaf(a1.y, x1.y, c1.y), 0.f);
        v[6] = (__bf16)fmaxf(fmaf(a1.z, x1.z, c1.z), 0.f);
        v[7] = (__bf16)fmaxf(fmaf(a1.w, x1.w, c1.w), 0.f);
        afrag[s] = v;
    }

    // ---------- phase 2: fc0 GEMM, W0 staged via double-buffered LDS ----------
    f32x4 acc[16];
    #pragma unroll
    for (int t = 0; t < 16; ++t) acc[t] = (f32x4){0.f, 0.f, 0.f, 0.f};

    const bf16x8* wsrc = (const bf16x8*)w0p;  // element idx = s*1024 + t*64 + lane
    bf16x8 stg[4];

    // prologue: stage k-step 0
    #pragma unroll
    for (int i = 0; i < 4; ++i) stg[i] = wsrc[i * 256 + tid];
    #pragma unroll
    for (int i = 0; i < 4; ++i) *(bf16x8*)&lds[0][(i * 256 + tid) * 8] = stg[i];
    __syncthreads();

    #pragma unroll
    for (int s = 0; s < 16; ++s) {
        const int cur = s & 1;
        if (s < 15) {  // issue next-slice global loads early
            #pragma unroll
            for (int i = 0; i < 4; ++i)
                stg[i] = wsrc[(s + 1) * 1024 + i * 256 + tid];
        }
        #pragma unroll
        for (int t = 0; t < 16; ++t) {
            const bf16x8 bfr = *(const bf16x8*)&lds[cur][(t * 64 + lane) * 8];
            acc[t] = __builtin_amdgcn_mfma_f32_16x16x32_bf16(afrag[s], bfr, acc[t], 0, 0, 0);
        }
        if (s < 15) {  // write-late into the other buffer
            #pragma unroll
            for (int i = 0; i < 4; ++i)
                *(bf16x8*)&lds[cur ^ 1][(i * 256 + tid) * 8] = stg[i];
        }
        __syncthreads();
    }

    // ---------- epilogue: fc BN+ReLU, fc1, ReLU, clamp ----------
    // C/D layout: col n = t*16 + (lane&15), row = (lane>>4)*4 + q
    const int nc = lane & 15;
    const int rq = (lane >> 4) << 2;
    float p0[4] = {0.f, 0.f, 0.f, 0.f};
    float p1[4] = {0.f, 0.f, 0.f, 0.f};
    #pragma unroll
    for (int t = 0; t < 16; ++t) {
        const int n = t * 16 + nc;
        const float A = A_fc[n], C = C_fc[n];
        const float w0n = W1[n], w1n = W1[256 + n];
        #pragma unroll
        for (int q = 0; q < 4; ++q) {
            const float h = fmaxf(fmaf(A, acc[t][q], C), 0.f);
            p0[q] = fmaf(h, w0n, p0[q]);
            p1[q] = fmaf(h, w1n, p1[q]);
        }
    }
    #pragma unroll
    for (int off = 1; off < 16; off <<= 1) {
        #pragma unroll
        for (int q = 0; q < 4; ++q) {
            p0[q] += __shfl_xor(p0[q], off, 64);
            p1[q] += __shfl_xor(p1[q], off, 64);
        }
    }
    if (nc < 8) {  // lane nc = q*2+m writes out[row(rq+q)][m] -> 32B/group coalesced
        const int q = nc >> 1, m = nc & 1;
        const float pq0 = (q == 0) ? p0[0] : (q == 1) ? p0[1] : (q == 2) ? p0[2] : p0[3];
        const float pq1 = (q == 0) ? p1[0] : (q == 1) ? p1[1] : (q == 2) ? p1[2] : p1[3];
        float v = (m == 0) ? pq0 : pq1;
        v = fmaxf(v + b1[m], 0.f);
        v = fminf(v, (m == 0) ? 512.f : 384.f);
        const size_t row = (size_t)blockIdx.x * MTILE + wave * 16 + rq + q;
        out[row * 2 + m] = v;
    }
}

extern "C" void kernel_launch(void* const* d_in, const int* in_sizes, int n_in,
                              void* d_out, int out_size, void* d_ws, size_t ws_size,
                              hipStream_t stream) {
    const float* frame_feat  = (const float*)d_in[0];
    const float* imu_feat    = (const float*)d_in[1];
    const float* imu_gamma   = (const float*)d_in[2];
    const float* imu_beta    = (const float*)d_in[3];
    const float* imu_mean    = (const float*)d_in[4];
    const float* imu_var     = (const float*)d_in[5];
    const float* frame_gamma = (const float*)d_in[6];
    const float* frame_beta  = (const float*)d_in[7];
    const float* frame_mean  = (const float*)d_in[8];
    const float* frame_var   = (const float*)d_in[9];
    const float* W0          = (const float*)d_in[10];
    const float* b0          = (const float*)d_in[11];
    const float* fc_gamma    = (const float*)d_in[12];
    const float* fc_beta     = (const float*)d_in[13];
    const float* fc_mean     = (const float*)d_in[14];
    const float* fc_var      = (const float*)d_in[15];
    const float* W1          = (const float*)d_in[16];
    const float* b1          = (const float*)d_in[17];

    setup_kernel<<<513, 256, 0, stream>>>(
        W0, imu_gamma, imu_beta, imu_mean, imu_var,
        frame_gamma, frame_beta, frame_mean, frame_var,
        b0, fc_gamma, fc_beta, fc_mean, fc_var, d_ws);

    fusion_main<<<NBLOCKS, 256, 0, stream>>>(
        frame_feat, imu_feat, W1, b1, d_ws, (float*)d_out);
}

// Round 2
// 92.903 us; speedup vs baseline: 1.0579x; 1.0579x over previous
//
#include <hip/hip_runtime.h>
#include <hip/hip_bf16.h>

typedef __bf16 bf16x8 __attribute__((ext_vector_type(8)));
typedef float  f32x4  __attribute__((ext_vector_type(4)));

#define BN_EPS 1e-5f
#define NROWS 131072
#define MTILE 64              // rows per block (4 waves x 16 rows)
#define NBLOCKS (NROWS / MTILE)

// counted vmcnt wait (never implicit vmcnt(0) from __syncthreads in the loops)
#define WAITVM(N) asm volatile("s_waitcnt vmcnt(" #N ")" ::: "memory")

__device__ __forceinline__ void gll16(const void* g, void* l) {
    // async global->LDS, 16B per lane; LDS dest = wave-uniform base + lane*16
    __builtin_amdgcn_global_load_lds(
        (const __attribute__((address_space(1))) void*)g,
        (__attribute__((address_space(3))) void*)l, 16, 0, 0);
}

// ws layout (bytes):
//   [0, 262144)        W0 packed bf16, fragment order [s][t][lane][8]
//   [262144, 264192)   a_fused f32[512]
//   [264192, 266240)   c_fused f32[512]
//   [266240, 267264)   A_fc f32[256]
//   [267264, 268288)   C_fc f32[256] (b0 folded in)

__global__ __launch_bounds__(256) void setup_kernel(
    const float* __restrict__ W0,
    const float* __restrict__ imu_gamma, const float* __restrict__ imu_beta,
    const float* __restrict__ imu_mean,  const float* __restrict__ imu_var,
    const float* __restrict__ frame_gamma, const float* __restrict__ frame_beta,
    const float* __restrict__ frame_mean,  const float* __restrict__ frame_var,
    const float* __restrict__ b0,
    const float* __restrict__ fc_gamma, const float* __restrict__ fc_beta,
    const float* __restrict__ fc_mean,  const float* __restrict__ fc_var,
    void* __restrict__ ws)
{
    __bf16* w0p    = (__bf16*)ws;
    float* a_fused = (float*)((char*)ws + 262144);
    float* c_fused = a_fused + 512;
    float* A_fc    = c_fused + 512;
    float* C_fc    = A_fc + 256;

    const int b = blockIdx.x;
    if (b < 512) {
        // pack W0[n][k] into B-fragment order:
        // flat = ((s*16 + t)*64 + lane)*8 + j ; n = t*16+(lane&15); k = s*32+(lane>>4)*8+j
        const int flat = b * 256 + threadIdx.x;
        const int j    = flat & 7;
        const int lane = (flat >> 3) & 63;
        const int t    = (flat >> 9) & 15;
        const int s    = flat >> 13;
        const int n    = t * 16 + (lane & 15);
        const int k    = s * 32 + ((lane >> 4) << 3) + j;
        w0p[flat] = (__bf16)W0[n * 512 + k];
    } else {
        const int t = threadIdx.x;
        const float af = frame_gamma[t] / sqrtf(frame_var[t] + BN_EPS);
        a_fused[t]       = af;
        c_fused[t]       = frame_beta[t] - frame_mean[t] * af;
        const float ai = imu_gamma[t] / sqrtf(imu_var[t] + BN_EPS);
        a_fused[256 + t] = ai;
        c_fused[256 + t] = imu_beta[t] - imu_mean[t] * ai;
        const float A = fc_gamma[t] / sqrtf(fc_var[t] + BN_EPS);
        A_fc[t] = A;
        C_fc[t] = fc_beta[t] - fc_mean[t] * A + A * b0[t];
    }
}

__global__ __launch_bounds__(256, 2) void fusion_main(
    const float* __restrict__ frame, const float* __restrict__ imu,
    const float* __restrict__ W1,    const float* __restrict__ b1,
    const void* __restrict__ ws_c,   float* __restrict__ out)
{
    const __bf16* w0p     = (const __bf16*)ws_c;
    const float*  a_fused = (const float*)((const char*)ws_c + 262144);
    const float*  c_fused = a_fused + 512;
    const float*  A_fc    = c_fused + 512;
    const float*  C_fc    = A_fc + 256;

    // 48 KB raw feature chunks (3-deep: depth-2 gll prefetch) + 32 KB W0 dbuf = 80 KB -> 2 blocks/CU
    __shared__ __align__(16) float  featbuf[3][4096];   // chunk = [64 rows][64 f32], XOR-swizzled granules
    __shared__ __align__(16) __bf16 w0buf[2][8192];     // 16 KB W0 k-slice x2

    const int tid  = threadIdx.x;
    const int wave = tid >> 6;
    const int lane = tid & 63;
    const int r    = lane & 15;   // A-frag row within wave tile
    const int kg   = lane >> 4;   // k-group
    const size_t rowBlk = (size_t)blockIdx.x * MTILE;

    // gll linear slot (16B units) f = i*256+tid -> row = i*16 + (tid>>4), stored granule G = tid&15.
    // Swizzle involution: stored G holds logical granule G ^ (row & 15). Pre-swizzle the GLOBAL source.
    const int rowi = tid >> 4;                 // 0..15
    const int Gp   = (lane & 15) ^ rowi;       // logical granule this lane fetches

    auto issue_feat = [&](int c) {
        float* base = featbuf[c % 3];
        const float* src = (c < 4) ? frame : imu;   // chunk c covers fused cols [c*64, c*64+64)
        const int col = (c & 3) * 64 + Gp * 4;      // within-modality f32 col
        #pragma unroll
        for (int i = 0; i < 4; ++i)
            gll16(src + (rowBlk + i * 16 + rowi) * 256 + col,
                  base + i * 1024 + wave * 256);
    };
    auto issue_w0 = [&](int s) {
        __bf16* base = w0buf[s & 1];
        const char* gb = (const char*)w0p + s * 16384 + tid * 16;
        #pragma unroll
        for (int i = 0; i < 4; ++i)
            gll16(gb + i * 4096, base + i * 2048 + wave * 512);
    };

    // ---------- phase 1: stream raw features via gll -> LDS, BN+ReLU+pack to A-frags ----------
    bf16x8 afrag[16];
    issue_feat(0);
    issue_feat(1);
    const int rbase = (wave * 16 + r) * 64;   // f32 index of this lane's row in a chunk

    #pragma unroll
    for (int c = 0; c < 8; ++c) {
        if (c < 6) issue_feat(c + 2);
        else if (c == 6) issue_w0(0);           // prefetch first W0 slice behind the feature stream
        if (c < 7) { WAITVM(8); } else { WAITVM(4); }
        __builtin_amdgcn_s_barrier();
        __builtin_amdgcn_sched_barrier(0);
        const float* fb = featbuf[c % 3];
        #pragma unroll
        for (int sl = 0; sl < 2; ++sl) {
            const int s  = c * 2 + sl;
            const int G0 = sl * 8 + kg * 2;
            const float4 x0 = *(const float4*)(fb + rbase + ((G0 ^ r) << 2));
            const float4 x1 = *(const float4*)(fb + rbase + (((G0 + 1) ^ r) << 2));
            const int kf = s * 32 + kg * 8;
            const float4 a0 = *(const float4*)(a_fused + kf);
            const float4 a1 = *(const float4*)(a_fused + kf + 4);
            const float4 c0 = *(const float4*)(c_fused + kf);
            const float4 c1 = *(const float4*)(c_fused + kf + 4);
            bf16x8 v;
            v[0] = (__bf16)fmaxf(fmaf(a0.x, x0.x, c0.x), 0.f);
            v[1] = (__bf16)fmaxf(fmaf(a0.y, x0.y, c0.y), 0.f);
            v[2] = (__bf16)fmaxf(fmaf(a0.z, x0.z, c0.z), 0.f);
            v[3] = (__bf16)fmaxf(fmaf(a0.w, x0.w, c0.w), 0.f);
            v[4] = (__bf16)fmaxf(fmaf(a1.x, x1.x, c1.x), 0.f);
            v[5] = (__bf16)fmaxf(fmaf(a1.y, x1.y, c1.y), 0.f);
            v[6] = (__bf16)fmaxf(fmaf(a1.z, x1.z, c1.z), 0.f);
            v[7] = (__bf16)fmaxf(fmaf(a1.w, x1.w, c1.w), 0.f);
            afrag[s] = v;
        }
        __builtin_amdgcn_s_barrier();
        __builtin_amdgcn_sched_barrier(0);
    }

    // ---------- phase 2: fc0 GEMM; W0 gll double-buffered, counted vmcnt (never 0 mid-loop) ----------
    f32x4 acc[16];
    #pragma unroll
    for (int t = 0; t < 16; ++t) acc[t] = (f32x4){0.f, 0.f, 0.f, 0.f};

    #pragma unroll
    for (int s = 0; s < 16; ++s) {
        if (s < 15) { issue_w0(s + 1); WAITVM(4); }
        else        { WAITVM(0); }
        __builtin_amdgcn_s_barrier();
        __builtin_amdgcn_sched_barrier(0);
        const __bf16* wb = w0buf[s & 1];
        #pragma unroll
        for (int t = 0; t < 16; ++t) {
            const bf16x8 bfr = *(const bf16x8*)(wb + (t * 64 + lane) * 8);
            acc[t] = __builtin_amdgcn_mfma_f32_16x16x32_bf16(afrag[s], bfr, acc[t], 0, 0, 0);
        }
        __builtin_amdgcn_s_barrier();
        __builtin_amdgcn_sched_barrier(0);
    }

    // ---------- epilogue: fc BN+ReLU, fc1, ReLU, clamp ----------
    // C/D layout: col n = t*16 + (lane&15), row = (lane>>4)*4 + q
    const int nc = lane & 15;
    const int rq = (lane >> 4) << 2;
    float p0[4] = {0.f, 0.f, 0.f, 0.f};
    float p1[4] = {0.f, 0.f, 0.f, 0.f};
    #pragma unroll
    for (int t = 0; t < 16; ++t) {
        const int n = t * 16 + nc;
        const float A = A_fc[n], C = C_fc[n];
        const float w0n = W1[n], w1n = W1[256 + n];
        #pragma unroll
        for (int q = 0; q < 4; ++q) {
            const float h = fmaxf(fmaf(A, acc[t][q], C), 0.f);
            p0[q] = fmaf(h, w0n, p0[q]);
            p1[q] = fmaf(h, w1n, p1[q]);
        }
    }
    #pragma unroll
    for (int off = 1; off < 16; off <<= 1) {
        #pragma unroll
        for (int q = 0; q < 4; ++q) {
            p0[q] += __shfl_xor(p0[q], off, 64);
            p1[q] += __shfl_xor(p1[q], off, 64);
        }
    }
    if (nc < 8) {  // lane nc = q*2+m writes out[row(rq+q)][m]
        const int q = nc >> 1, m = nc & 1;
        const float pq0 = (q == 0) ? p0[0] : (q == 1) ? p0[1] : (q == 2) ? p0[2] : p0[3];
        const float pq1 = (q == 0) ? p1[0] : (q == 1) ? p1[1] : (q == 2) ? p1[2] : p1[3];
        float v = (m == 0) ? pq0 : pq1;
        v = fmaxf(v + b1[m], 0.f);
        v = fminf(v, (m == 0) ? 512.f : 384.f);
        const size_t row = rowBlk + wave * 16 + rq + q;
        out[row * 2 + m] = v;
    }
}

extern "C" void kernel_launch(void* const* d_in, const int* in_sizes, int n_in,
                              void* d_out, int out_size, void* d_ws, size_t ws_size,
                              hipStream_t stream) {
    const float* frame_feat  = (const float*)d_in[0];
    const float* imu_feat    = (const float*)d_in[1];
    const float* imu_gamma   = (const float*)d_in[2];
    const float* imu_beta    = (const float*)d_in[3];
    const float* imu_mean    = (const float*)d_in[4];
    const float* imu_var     = (const float*)d_in[5];
    const float* frame_gamma = (const float*)d_in[6];
    const float* frame_beta  = (const float*)d_in[7];
    const float* frame_mean  = (const float*)d_in[8];
    const float* frame_var   = (const float*)d_in[9];
    const float* W0          = (const float*)d_in[10];
    const float* b0          = (const float*)d_in[11];
    const float* fc_gamma    = (const float*)d_in[12];
    const float* fc_beta     = (const float*)d_in[13];
    const float* fc_mean     = (const float*)d_in[14];
    const float* fc_var      = (const float*)d_in[15];
    const float* W1          = (const float*)d_in[16];
    const float* b1          = (const float*)d_in[17];

    setup_kernel<<<513, 256, 0, stream>>>(
        W0, imu_gamma, imu_beta, imu_mean, imu_var,
        frame_gamma, frame_beta, frame_mean, frame_var,
        b0, fc_gamma, fc_beta, fc_mean, fc_var, d_ws);

    fusion_main<<<NBLOCKS, 256, 0, stream>>>(
        frame_feat, imu_feat, W1, b1, d_ws, (float*)d_out);
}